// Round 2
// baseline (347.585 us; speedup 1.0000x reference)
//
#include <hip/hip_runtime.h>

#define N 8192
#define LOGN 13
#define IN_DIM 128
#define HID 64
#define NC 2
#define MLPW 64
#define NWORDS (N * (size_t)N / 32)   // 2,097,152 bitmask words

// ---------------- kernel 1: dedup only (no gathers, no MLP) ----------------
__global__ void dedup_kernel(const int* __restrict__ idx, int E,
                             unsigned int* __restrict__ bitmask,
                             int* __restrict__ uniq_cnt,
                             int* __restrict__ uniq_idx,
                             int* __restrict__ row_cnt,
                             int* __restrict__ col_cnt)
{
    int e = blockIdx.x * blockDim.x + threadIdx.x;
    if (e >= E) return;
    int g = idx[e];
    unsigned int word = ((unsigned int)g) >> 5;
    unsigned int bit = 1u << (g & 31);
    unsigned int old = atomicOr(&bitmask[word], bit);
    if (old & bit) return;                  // duplicate: already claimed
    int u = atomicAdd(uniq_cnt, 1);
    uniq_idx[u] = g;
    atomicAdd(&row_cnt[g >> LOGN], 1);
    atomicAdd(&col_cnt[g & (N - 1)], 1);
}

// ---------------- kernel 2: fused zero-fill + edge MLP + ordered scatter ----------------
// Each block owns 256 bitmask words = 8192 output floats (32 KB), staged in LDS.
// adj gather is skipped: adj.flat[idx] == 1.0 by construction.
__global__ __launch_bounds__(256) void mask_kernel(
    const unsigned int* __restrict__ bitmask,
    const float* __restrict__ xdeg,
    const float* __restrict__ ydeg,
    const float* __restrict__ Wm1,
    const float* __restrict__ bm1,
    const float* __restrict__ Wm2,
    const float* __restrict__ bm2,
    float* __restrict__ adj_mask)
{
    __shared__ float swx[MLPW], swy[MLPW], sb[MLPW], sw2[MLPW];
    __shared__ float sp[256 * 32];          // 32 KB staging tile
    int t = threadIdx.x;
    if (t < MLPW) {
        swx[t] = Wm1[MLPW + t];             // weight on xdeg feature
        swy[t] = Wm1[2 * MLPW + t];         // weight on ydeg feature
        sb[t]  = Wm1[t] + bm1[t];           // adj feature == 1.0 folded into bias
        sw2[t] = Wm2[2 * t] - Wm2[2 * t + 1]; // for (l0 - l1)
    }
    float4 z4 = {0.f, 0.f, 0.f, 0.f};
#pragma unroll
    for (int i = 0; i < 8; i++) ((float4*)sp)[t + i * 256] = z4;
    __syncthreads();

    size_t wordbase = (size_t)blockIdx.x * 256;
    unsigned int w = bitmask[wordbase + t];
    float bias_l = bm2[0] - bm2[1];
    while (w) {
        int b = __ffs(w) - 1;
        w &= w - 1;
        size_t g = ((wordbase + t) << 5) | (unsigned)b;
        float f1 = xdeg[g];
        float f2 = ydeg[g];
        float dl = bias_l;
#pragma unroll 8
        for (int j = 0; j < MLPW; j++) {
            float h = fmaxf(f1 * swx[j] + f2 * swy[j] + sb[j], 0.0f);
            dl += h * sw2[j];
        }
        sp[t * 32 + b] = 1.0f / (1.0f + expf(dl));   // softmax[:,1]
    }
    __syncthreads();
    float4* dst = (float4*)(adj_mask + (wordbase << 5));
#pragma unroll
    for (int i = 0; i < 8; i++) dst[t + i * 256] = ((float4*)sp)[t + i * 256];
}

// ---------------- kernel 3: degree -> D^{-1/2} ----------------
__global__ void deg_kernel(const int* __restrict__ row_cnt, const int* __restrict__ col_cnt,
                           float* __restrict__ drow, float* __restrict__ dcol)
{
    int i = blockIdx.x * blockDim.x + threadIdx.x;
    if (i < N) {
        drow[i] = 1.0f / sqrtf((float)(row_cnt[i] + 1));   // +1 from identity
        dcol[i] = 1.0f / sqrtf((float)(col_cnt[i] + 1));
    }
}

// ---------------- kernel 4: exclusive prefix scan of row counts (one block) ----------------
__global__ void scan_kernel(const int* __restrict__ row_cnt, int* __restrict__ row_ptr)
{
    __shared__ int tot[1024];
    int t = threadIdx.x;
    int base = t * 8;
    int loc[8];
    int s = 0;
    for (int i = 0; i < 8; i++) { loc[i] = s; s += row_cnt[base + i]; }
    tot[t] = s;
    __syncthreads();
    for (int off = 1; off < 1024; off <<= 1) {
        int v = (t >= off) ? tot[t - off] : 0;
        __syncthreads();
        tot[t] += v;
        __syncthreads();
    }
    int excl = tot[t] - s;
    for (int i = 0; i < 8; i++) row_ptr[base + i] = excl + loc[i];
    if (t == 1023) row_ptr[N] = tot[1023];
}

// ---------------- kernel 5: scatter unique edges into CSR buckets ----------------
__global__ void fill_kernel(const int* __restrict__ uniq_cnt,
                            const int* __restrict__ uniq_idx,
                            const int* __restrict__ row_ptr,
                            int* __restrict__ row_fill,
                            int* __restrict__ csr_col)
{
    int u = blockIdx.x * blockDim.x + threadIdx.x;
    if (u >= *uniq_cnt) return;
    int g = uniq_idx[u];
    int r = g >> LOGN;
    int pos = atomicAdd(&row_fill[r], 1);
    csr_col[row_ptr[r] + pos] = g & (N - 1);
}

// ---------------- kernel 6: Y[j][d] = dcol[j] * (x[j,:] @ W1[:,d]) ----------------
__global__ __launch_bounds__(256) void xw1_kernel(const float* __restrict__ x,
                                                  const float* __restrict__ W1,
                                                  const float* __restrict__ dcol,
                                                  float* __restrict__ Y)
{
    __shared__ float sx[4][IN_DIM];
    int r0 = blockIdx.x * 4;
    for (int t = threadIdx.x; t < 4 * IN_DIM; t += 256)
        sx[t >> 7][t & 127] = x[(size_t)(r0 + (t >> 7)) * IN_DIM + (t & 127)];
    __syncthreads();
    int rr = threadIdx.x >> 6;
    int d = threadIdx.x & 63;
    float acc = 0.0f;
#pragma unroll 8
    for (int k = 0; k < IN_DIM; k++)
        acc += sx[rr][k] * W1[k * HID + d];
    int j = r0 + rr;
    Y[(size_t)j * HID + d] = dcol[j] * acc;
}

// ---------------- kernel 7: SpMM layer 1: hid = drow ⊙ (A @ Y + Y) ----------------
__global__ __launch_bounds__(256) void spmm1_kernel(const float* __restrict__ Y,
                                                    const int* __restrict__ row_ptr,
                                                    const int* __restrict__ csr_col,
                                                    const float* __restrict__ drow,
                                                    float* __restrict__ hid)
{
    int r = blockIdx.x * 4 + (threadIdx.x >> 6);
    int d = threadIdx.x & 63;
    int s = row_ptr[r], e = row_ptr[r + 1];
    float acc = Y[(size_t)r * HID + d];          // identity (+I) term
    int k = s;
    for (; k + 3 < e; k += 4) {
        int c0 = csr_col[k], c1 = csr_col[k + 1], c2 = csr_col[k + 2], c3 = csr_col[k + 3];
        acc += Y[(size_t)c0 * HID + d];
        acc += Y[(size_t)c1 * HID + d];
        acc += Y[(size_t)c2 * HID + d];
        acc += Y[(size_t)c3 * HID + d];
    }
    for (; k < e; k++) acc += Y[(size_t)csr_col[k] * HID + d];
    hid[(size_t)r * HID + d] = drow[r] * acc;
}

// ---------------- kernel 8: Zc[j] = dcol[j] * (hid[j,:] @ W2) ----------------
__global__ __launch_bounds__(256) void zc_kernel(const float* __restrict__ hid,
                                                 const float* __restrict__ W2,
                                                 const float* __restrict__ dcol,
                                                 float* __restrict__ Zc)
{
    int r = blockIdx.x * 4 + (threadIdx.x >> 6);
    int lane = threadIdx.x & 63;
    float h = hid[(size_t)r * HID + lane];
    float z0 = h * W2[lane * 2 + 0];
    float z1 = h * W2[lane * 2 + 1];
    for (int off = 32; off >= 1; off >>= 1) {
        z0 += __shfl_xor(z0, off, 64);
        z1 += __shfl_xor(z1, off, 64);
    }
    if (lane == 0) {
        Zc[r * 2 + 0] = dcol[r] * z0;
        Zc[r * 2 + 1] = dcol[r] * z1;
    }
}

// ---------------- kernel 9: SpMM layer 2: out = drow ⊙ (A @ Zc + Zc) ----------------
__global__ __launch_bounds__(256) void spmm2_kernel(const float* __restrict__ Zc,
                                                    const int* __restrict__ row_ptr,
                                                    const int* __restrict__ csr_col,
                                                    const float* __restrict__ drow,
                                                    float* __restrict__ out)
{
    int r = blockIdx.x * 4 + (threadIdx.x >> 6);
    int lane = threadIdx.x & 63;
    int s = row_ptr[r], e = row_ptr[r + 1];
    float a0 = 0.0f, a1 = 0.0f;
    for (int k = s + lane; k < e; k += 64) {
        int c = csr_col[k];
        a0 += Zc[c * 2 + 0];
        a1 += Zc[c * 2 + 1];
    }
    for (int off = 32; off >= 1; off >>= 1) {
        a0 += __shfl_xor(a0, off, 64);
        a1 += __shfl_xor(a1, off, 64);
    }
    if (lane == 0) {
        a0 += Zc[r * 2 + 0];                     // identity (+I) term
        a1 += Zc[r * 2 + 1];
        out[r * 2 + 0] = drow[r] * a0;
        out[r * 2 + 1] = drow[r] * a1;
    }
}

extern "C" void kernel_launch(void* const* d_in, const int* in_sizes, int n_in,
                              void* d_out, int out_size, void* d_ws, size_t ws_size,
                              hipStream_t stream)
{
    const float* x    = (const float*)d_in[0];
    // d_in[1] (adj) is not needed: adj.flat[idx] == 1.0 by construction
    const float* xdeg = (const float*)d_in[2];
    const float* ydeg = (const float*)d_in[3];
    const float* Wm1  = (const float*)d_in[4];
    const float* bm1  = (const float*)d_in[5];
    const float* Wm2  = (const float*)d_in[6];
    const float* bm2  = (const float*)d_in[7];
    const float* W1   = (const float*)d_in[8];
    const float* W2   = (const float*)d_in[9];
    const int*   idx  = (const int*)d_in[10];
    const int E = in_sizes[10];

    float* out = (float*)d_out;                       // [N*NC]
    float* adj_mask = out + (size_t)N * NC;           // [N*N]

    // ---- workspace carve (~18 MB) ----
    char* ws = (char*)d_ws;
    size_t off = 0;
    auto carve = [&](size_t bytes) -> void* {
        void* p = ws + off;
        off += (bytes + 255) & ~(size_t)255;
        return p;
    };
    unsigned int* bitmask = (unsigned int*)carve(NWORDS * sizeof(unsigned int));
    int* uniq_cnt = (int*)carve(sizeof(int));
    int* uniq_idx = (int*)carve((size_t)E * sizeof(int));
    int* row_cnt  = (int*)carve((size_t)N * sizeof(int));
    int* col_cnt  = (int*)carve((size_t)N * sizeof(int));
    int* row_ptr  = (int*)carve((size_t)(N + 1) * sizeof(int));
    int* row_fill = (int*)carve((size_t)N * sizeof(int));
    int* csr_col  = (int*)carve((size_t)E * sizeof(int));
    float* drow   = (float*)carve((size_t)N * sizeof(float));
    float* dcol   = (float*)carve((size_t)N * sizeof(float));
    float* Y      = (float*)carve((size_t)N * HID * sizeof(float));
    float* hid    = (float*)carve((size_t)N * HID * sizeof(float));
    float* Zc     = (float*)carve((size_t)N * NC * sizeof(float));

    hipMemsetAsync(bitmask, 0, NWORDS * sizeof(unsigned int), stream);
    hipMemsetAsync(uniq_cnt, 0, sizeof(int), stream);
    hipMemsetAsync(row_cnt, 0, (size_t)N * sizeof(int), stream);
    hipMemsetAsync(col_cnt, 0, (size_t)N * sizeof(int), stream);
    hipMemsetAsync(row_fill, 0, (size_t)N * sizeof(int), stream);
    // NOTE: no adj_mask memset — mask_kernel writes every byte of it.

    int eb = (E + 255) / 256;
    dedup_kernel<<<eb, 256, 0, stream>>>(idx, E, bitmask, uniq_cnt, uniq_idx, row_cnt, col_cnt);
    mask_kernel<<<NWORDS / 256, 256, 0, stream>>>(bitmask, xdeg, ydeg, Wm1, bm1, Wm2, bm2, adj_mask);
    deg_kernel<<<(N + 255) / 256, 256, 0, stream>>>(row_cnt, col_cnt, drow, dcol);
    scan_kernel<<<1, 1024, 0, stream>>>(row_cnt, row_ptr);
    fill_kernel<<<eb, 256, 0, stream>>>(uniq_cnt, uniq_idx, row_ptr, row_fill, csr_col);
    xw1_kernel<<<N / 4, 256, 0, stream>>>(x, W1, dcol, Y);
    spmm1_kernel<<<N / 4, 256, 0, stream>>>(Y, row_ptr, csr_col, drow, hid);
    zc_kernel<<<N / 4, 256, 0, stream>>>(hid, W2, dcol, Zc);
    spmm2_kernel<<<N / 4, 256, 0, stream>>>(Zc, row_ptr, csr_col, drow, out);
}

// Round 3
// 191.386 us; speedup vs baseline: 1.8161x; 1.8161x over previous
//
#include <hip/hip_runtime.h>

#define N 8192
#define LOGN 13
#define IN_DIM 128
#define HID 64
#define NC 2
#define MLPW 64
#define NWORDS (N * (size_t)N / 32)   // 2,097,152 bitmask words

typedef unsigned int uint;
typedef float f4 __attribute__((ext_vector_type(4)));

// ---------------- kernel 1: fire-and-forget bitmask build ----------------
// No return value used -> non-returning global_atomic_or, no latency chain,
// no uniq compaction, no contended counter.
__global__ void dedup_or_kernel(const int* __restrict__ idx, int E,
                                uint* __restrict__ bitmask)
{
    int e = blockIdx.x * blockDim.x + threadIdx.x;
    if (e >= E) return;
    uint g = (uint)idx[e];
    atomicOr(&bitmask[g >> 5], 1u << (g & 31));
}

// ---------------- kernel 2: fused zero-fill + edge MLP + degrees ----------------
// One block per adjacency ROW (256 words = 8192 cols = 32 KB of output).
// Produces: adj_mask row (dense, nt-stores), drow[r] (popcount), col_cnt (atomics).
// adj feature == 1.0 by construction (adj was built by scattering 1.0 at idx).
__global__ __launch_bounds__(256) void mask_kernel(
    const uint* __restrict__ bitmask,
    const float* __restrict__ xdeg,
    const float* __restrict__ ydeg,
    const float* __restrict__ Wm1,
    const float* __restrict__ bm1,
    const float* __restrict__ Wm2,
    const float* __restrict__ bm2,
    float* __restrict__ adj_mask,
    float* __restrict__ drow,
    int* __restrict__ col_cnt)
{
    __shared__ float swx[MLPW], swy[MLPW], sb[MLPW], sw2[MLPW];
    __shared__ float sp[256 * 32];          // 32 KB staging tile (one row)
    __shared__ int spc[4];
    int t = threadIdx.x;
    if (t < MLPW) {
        swx[t] = Wm1[MLPW + t];                 // weight on xdeg feature
        swy[t] = Wm1[2 * MLPW + t];             // weight on ydeg feature
        sb[t]  = Wm1[t] + bm1[t];               // adj==1.0 folded into bias
        sw2[t] = Wm2[2 * t] - Wm2[2 * t + 1];   // for (l0 - l1)
    }
    f4 z4 = {0.f, 0.f, 0.f, 0.f};
#pragma unroll
    for (int i = 0; i < 8; i++) ((f4*)sp)[t + i * 256] = z4;
    __syncthreads();

    int r = blockIdx.x;
    uint w = bitmask[(size_t)r * 256 + t];
    int pc = __popc(w);
    float bias_l = bm2[0] - bm2[1];
    size_t rowbase = (size_t)r * N;
    while (w) {
        int b = __ffs(w) - 1;
        w &= w - 1;
        int c = t * 32 + b;
        float f1 = xdeg[rowbase + c];
        float f2 = ydeg[rowbase + c];
        float dl = bias_l;
#pragma unroll 8
        for (int j = 0; j < MLPW; j++) {
            float h = fmaxf(f1 * swx[j] + f2 * swy[j] + sb[j], 0.0f);
            dl += h * sw2[j];
        }
        sp[t * 32 + b] = 1.0f / (1.0f + expf(dl));   // softmax[:,1]
        atomicAdd(&col_cnt[c], 1);                   // fire-and-forget
    }

    // row degree = sum of popcounts (unique by construction of the bitmask)
    for (int off = 32; off >= 1; off >>= 1) pc += __shfl_down(pc, off, 64);
    if ((t & 63) == 0) spc[t >> 6] = pc;
    __syncthreads();
    if (t == 0)
        drow[r] = 1.0f / sqrtf((float)(spc[0] + spc[1] + spc[2] + spc[3] + 1));

    // stream the finished row out with non-temporal stores (don't pollute L2)
    f4* dst = (f4*)(adj_mask + rowbase);
#pragma unroll
    for (int i = 0; i < 8; i++)
        __builtin_nontemporal_store(((f4*)sp)[t + i * 256], dst + t + i * 256);
}

// ---------------- kernel 3: column degree -> D^{-1/2} ----------------
__global__ void dcol_kernel(const int* __restrict__ col_cnt, float* __restrict__ dcol)
{
    int i = blockIdx.x * blockDim.x + threadIdx.x;
    if (i < N) dcol[i] = 1.0f / sqrtf((float)(col_cnt[i] + 1));  // +1 from identity
}

// ---------------- kernel 4: Y[j][d] = dcol[j] * (x[j,:] @ W1[:,d]) ----------------
__global__ __launch_bounds__(256) void xw1_kernel(const float* __restrict__ x,
                                                  const float* __restrict__ W1,
                                                  const float* __restrict__ dcol,
                                                  float* __restrict__ Y)
{
    __shared__ float sx[4][IN_DIM];
    int r0 = blockIdx.x * 4;
    for (int t = threadIdx.x; t < 4 * IN_DIM; t += 256)
        sx[t >> 7][t & 127] = x[(size_t)(r0 + (t >> 7)) * IN_DIM + (t & 127)];
    __syncthreads();
    int rr = threadIdx.x >> 6;
    int d = threadIdx.x & 63;
    float acc = 0.0f;
#pragma unroll 8
    for (int k = 0; k < IN_DIM; k++)
        acc += sx[rr][k] * W1[k * HID + d];
    int j = r0 + rr;
    Y[(size_t)j * HID + d] = dcol[j] * acc;
}

// ---------------- kernel 5: SpMM layer 1 straight off the bitmask ----------------
// wave per row, lane = feature d; bits of a word are sorted cols -> deterministic.
__global__ __launch_bounds__(256) void spmm1_kernel(const float* __restrict__ Y,
                                                    const uint* __restrict__ bitmask,
                                                    const float* __restrict__ drow,
                                                    float* __restrict__ hid)
{
    int r = blockIdx.x * 4 + (threadIdx.x >> 6);
    int d = threadIdx.x & 63;
    const uint4* wp = (const uint4*)(bitmask + (size_t)r * 256);
    float acc0 = Y[(size_t)r * HID + d];         // identity (+I) term
    float acc1 = 0.0f;
    for (int q = 0; q < 64; q++) {
        uint4 wv = wp[q];                        // wave-uniform 16B broadcast load
        uint w0 = wv.x, w1 = wv.y, w2 = wv.z, w3 = wv.w;
        int cb = q * 128;
        while (w0) { int b = __ffs(w0) - 1; w0 &= w0 - 1; acc0 += Y[(size_t)(cb +      b) * HID + d]; }
        while (w1) { int b = __ffs(w1) - 1; w1 &= w1 - 1; acc1 += Y[(size_t)(cb + 32 + b) * HID + d]; }
        while (w2) { int b = __ffs(w2) - 1; w2 &= w2 - 1; acc0 += Y[(size_t)(cb + 64 + b) * HID + d]; }
        while (w3) { int b = __ffs(w3) - 1; w3 &= w3 - 1; acc1 += Y[(size_t)(cb + 96 + b) * HID + d]; }
    }
    hid[(size_t)r * HID + d] = drow[r] * (acc0 + acc1);
}

// ---------------- kernel 6: Zc[j] = dcol[j] * (hid[j,:] @ W2) ----------------
__global__ __launch_bounds__(256) void zc_kernel(const float* __restrict__ hid,
                                                 const float* __restrict__ W2,
                                                 const float* __restrict__ dcol,
                                                 float* __restrict__ Zc)
{
    int r = blockIdx.x * 4 + (threadIdx.x >> 6);
    int lane = threadIdx.x & 63;
    float h = hid[(size_t)r * HID + lane];
    float z0 = h * W2[lane * 2 + 0];
    float z1 = h * W2[lane * 2 + 1];
    for (int off = 32; off >= 1; off >>= 1) {
        z0 += __shfl_xor(z0, off, 64);
        z1 += __shfl_xor(z1, off, 64);
    }
    if (lane == 0) {
        Zc[r * 2 + 0] = dcol[r] * z0;
        Zc[r * 2 + 1] = dcol[r] * z1;
    }
}

// ---------------- kernel 7: SpMM layer 2 off the bitmask ----------------
// wave per row, lanes parallel over words, shuffle-reduce at the end.
__global__ __launch_bounds__(256) void spmm2_kernel(const float* __restrict__ Zc,
                                                    const uint* __restrict__ bitmask,
                                                    const float* __restrict__ drow,
                                                    float* __restrict__ out)
{
    int r = blockIdx.x * 4 + (threadIdx.x >> 6);
    int lane = threadIdx.x & 63;
    float a0 = 0.0f, a1 = 0.0f;
#pragma unroll
    for (int i = 0; i < 4; i++) {
        int wi = lane + i * 64;
        uint w = bitmask[(size_t)r * 256 + wi];
        int cb = wi * 32;
        while (w) {
            int b = __ffs(w) - 1;
            w &= w - 1;
            a0 += Zc[(cb + b) * 2 + 0];
            a1 += Zc[(cb + b) * 2 + 1];
        }
    }
    for (int off = 32; off >= 1; off >>= 1) {
        a0 += __shfl_xor(a0, off, 64);
        a1 += __shfl_xor(a1, off, 64);
    }
    if (lane == 0) {
        a0 += Zc[r * 2 + 0];                     // identity (+I) term
        a1 += Zc[r * 2 + 1];
        out[r * 2 + 0] = drow[r] * a0;
        out[r * 2 + 1] = drow[r] * a1;
    }
}

extern "C" void kernel_launch(void* const* d_in, const int* in_sizes, int n_in,
                              void* d_out, int out_size, void* d_ws, size_t ws_size,
                              hipStream_t stream)
{
    const float* x    = (const float*)d_in[0];
    // d_in[1] (adj) unused: adj.flat[idx] == 1.0 by construction
    const float* xdeg = (const float*)d_in[2];
    const float* ydeg = (const float*)d_in[3];
    const float* Wm1  = (const float*)d_in[4];
    const float* bm1  = (const float*)d_in[5];
    const float* Wm2  = (const float*)d_in[6];
    const float* bm2  = (const float*)d_in[7];
    const float* W1   = (const float*)d_in[8];
    const float* W2   = (const float*)d_in[9];
    const int*   idx  = (const int*)d_in[10];
    const int E = in_sizes[10];

    float* out = (float*)d_out;                       // [N*NC]
    float* adj_mask = out + (size_t)N * NC;           // [N*N]

    // ---- workspace carve (~12.3 MB) ----
    char* ws = (char*)d_ws;
    size_t off = 0;
    auto carve = [&](size_t bytes) -> void* {
        void* p = ws + off;
        off += (bytes + 255) & ~(size_t)255;
        return p;
    };
    uint* bitmask = (uint*)carve(NWORDS * sizeof(uint));
    int* col_cnt  = (int*)carve((size_t)N * sizeof(int));
    float* drow   = (float*)carve((size_t)N * sizeof(float));
    float* dcol   = (float*)carve((size_t)N * sizeof(float));
    float* Y      = (float*)carve((size_t)N * HID * sizeof(float));
    float* hid    = (float*)carve((size_t)N * HID * sizeof(float));
    float* Zc     = (float*)carve((size_t)N * NC * sizeof(float));

    hipMemsetAsync(bitmask, 0, NWORDS * sizeof(uint), stream);
    hipMemsetAsync(col_cnt, 0, (size_t)N * sizeof(int), stream);

    dedup_or_kernel<<<(E + 255) / 256, 256, 0, stream>>>(idx, E, bitmask);
    mask_kernel<<<N, 256, 0, stream>>>(bitmask, xdeg, ydeg, Wm1, bm1, Wm2, bm2,
                                       adj_mask, drow, col_cnt);
    dcol_kernel<<<(N + 255) / 256, 256, 0, stream>>>(col_cnt, dcol);
    xw1_kernel<<<N / 4, 256, 0, stream>>>(x, W1, dcol, Y);
    spmm1_kernel<<<N / 4, 256, 0, stream>>>(Y, bitmask, drow, hid);
    zc_kernel<<<N / 4, 256, 0, stream>>>(hid, W2, dcol, Zc);
    spmm2_kernel<<<N / 4, 256, 0, stream>>>(Zc, bitmask, drow, out);
}

// Round 4
// 153.442 us; speedup vs baseline: 2.2653x; 1.2473x over previous
//
#include <hip/hip_runtime.h>

#define N 8192
#define LOGN 13
#define IN_DIM 128
#define HID 64
#define NC 2
#define MLPW 64
#define NWORDS (N * (size_t)N / 32)   // 2,097,152 bitmask words
#define CAP 1024                      // per-row edge list capacity (avg deg ~79)

typedef unsigned int uint;
typedef float f4 __attribute__((ext_vector_type(4)));

// ---------------- kernel 1: fire-and-forget bitmask build ----------------
__global__ void dedup_or_kernel(const int* __restrict__ idx, int E,
                                uint* __restrict__ bitmask)
{
    int e = blockIdx.x * blockDim.x + threadIdx.x;
    if (e >= E) return;
    uint g = (uint)idx[e];
    atomicOr(&bitmask[g >> 5], 1u << (g & 31));
}

// per-edge MLP with adj-feature folded into bias; returns softmax[:,1]
__device__ __forceinline__ float edge_mlp(float f1, float f2, float bias_l,
                                          const float* swx, const float* swy,
                                          const float* sb, const float* sw2)
{
    float dl = bias_l;
#pragma unroll 8
    for (int j = 0; j < MLPW; j++) {
        float h = fmaxf(f1 * swx[j] + f2 * swy[j] + sb[j], 0.0f);
        dl += h * sw2[j];
    }
    return 1.0f / (1.0f + expf(dl));
}

// ---------------- kernel 2: fused zero-fill + compacted edge MLP + degrees ----------------
// One block per adjacency ROW. Compacts set bits into an LDS list, then runs
// the MLP densely (all lanes active) instead of inside the divergent bit-walk.
__global__ __launch_bounds__(256) void mask_kernel(
    const uint* __restrict__ bitmask,
    const float* __restrict__ xdeg,
    const float* __restrict__ ydeg,
    const float* __restrict__ Wm1,
    const float* __restrict__ bm1,
    const float* __restrict__ Wm2,
    const float* __restrict__ bm2,
    float* __restrict__ adj_mask,
    float* __restrict__ drow,
    int* __restrict__ col_cnt)
{
    __shared__ float swx[MLPW], swy[MLPW], sb[MLPW], sw2[MLPW];
    __shared__ float sp[256 * 32];          // 32 KB staging tile (one row)
    __shared__ int list[CAP];
    __shared__ int cnt;
    __shared__ int spc[4];
    int t = threadIdx.x;
    if (t < MLPW) {
        swx[t] = Wm1[MLPW + t];                 // weight on xdeg feature
        swy[t] = Wm1[2 * MLPW + t];             // weight on ydeg feature
        sb[t]  = Wm1[t] + bm1[t];               // adj==1.0 folded into bias
        sw2[t] = Wm2[2 * t] - Wm2[2 * t + 1];   // for (l0 - l1)
    }
    if (t == 0) cnt = 0;
    f4 z4 = {0.f, 0.f, 0.f, 0.f};
#pragma unroll
    for (int i = 0; i < 8; i++) ((f4*)sp)[t + i * 256] = z4;
    __syncthreads();

    int r = blockIdx.x;
    size_t rowbase = (size_t)r * N;
    float bias_l = bm2[0] - bm2[1];
    uint w = bitmask[(size_t)r * 256 + t];
    int pc = __popc(w);
    // compact set bits into LDS list (cheap divergent phase: LDS atomics only)
    while (w) {
        int b = __ffs(w) - 1;
        w &= w - 1;
        int c = t * 32 + b;
        int p = atomicAdd(&cnt, 1);
        if (p < CAP) {
            list[p] = c;
        } else {                                 // overflow fallback (never for avg deg 79)
            float pv = edge_mlp(xdeg[rowbase + c], ydeg[rowbase + c], bias_l, swx, swy, sb, sw2);
            sp[c] = pv;
            atomicAdd(&col_cnt[c], 1);
        }
    }
    __syncthreads();
    int n = min(cnt, CAP);
    // dense MLP phase: one edge per thread, all lanes active
    for (int i = t; i < n; i += 256) {
        int c = list[i];
        float pv = edge_mlp(xdeg[rowbase + c], ydeg[rowbase + c], bias_l, swx, swy, sb, sw2);
        sp[c] = pv;
        atomicAdd(&col_cnt[c], 1);              // fire-and-forget
    }

    // row degree = sum of popcounts (bits are unique by construction)
    for (int off = 32; off >= 1; off >>= 1) pc += __shfl_down(pc, off, 64);
    if ((t & 63) == 0) spc[t >> 6] = pc;
    __syncthreads();                             // also fences sp[] writes
    if (t == 0)
        drow[r] = 1.0f / sqrtf((float)(spc[0] + spc[1] + spc[2] + spc[3] + 1));

    // stream the finished row out with non-temporal stores
    f4* dst = (f4*)(adj_mask + rowbase);
#pragma unroll
    for (int i = 0; i < 8; i++)
        __builtin_nontemporal_store(((f4*)sp)[t + i * 256], dst + t + i * 256);
}

// ---------------- kernel 3: Y[j][d] = dcol[j] * (x[j,:] @ W1[:,d]) ----------------
// dcol computed inline from col_cnt (kernel deleted).
__global__ __launch_bounds__(256) void xw1_kernel(const float* __restrict__ x,
                                                  const float* __restrict__ W1,
                                                  const int* __restrict__ col_cnt,
                                                  float* __restrict__ Y)
{
    __shared__ float sx[4][IN_DIM];
    int r0 = blockIdx.x * 4;
    for (int t = threadIdx.x; t < 4 * IN_DIM; t += 256)
        sx[t >> 7][t & 127] = x[(size_t)(r0 + (t >> 7)) * IN_DIM + (t & 127)];
    __syncthreads();
    int rr = threadIdx.x >> 6;
    int d = threadIdx.x & 63;
    float acc = 0.0f;
#pragma unroll 8
    for (int k = 0; k < IN_DIM; k++)
        acc += sx[rr][k] * W1[k * HID + d];
    int j = r0 + rr;
    float dc = 1.0f / sqrtf((float)(col_cnt[j] + 1));
    Y[(size_t)j * HID + d] = dc * acc;
}

// ---------------- kernel 4: fused SpMM layer 1 + W2 projection + dcol ----------------
// hid[r][:] never materialized: hv = drow[r]*(A@Y + Y)[r][d] lives in a register,
// immediately projected: Zc[r] = dcol[r] * (hv @ W2). Row index readfirstlane'd
// so bitmask loads go to the scalar pipe.
__global__ __launch_bounds__(256) void spmm1_kernel(const float* __restrict__ Y,
                                                    const uint* __restrict__ bitmask,
                                                    const float* __restrict__ drow,
                                                    const int* __restrict__ col_cnt,
                                                    const float* __restrict__ W2,
                                                    float* __restrict__ Zc)
{
    int r = blockIdx.x * 4 + (threadIdx.x >> 6);
    r = __builtin_amdgcn_readfirstlane(r);       // wave-uniform -> SGPR
    int d = threadIdx.x & 63;
    const uint4* wp = (const uint4*)(bitmask + (size_t)r * 256);
    float acc0 = Y[(size_t)r * HID + d];         // identity (+I) term
    float acc1 = 0.0f;
    for (int q = 0; q < 64; q++) {
        uint4 wv = wp[q];                        // scalar s_load_dwordx4
        uint w0 = wv.x, w1 = wv.y, w2 = wv.z, w3 = wv.w;
        int cb = q * 128;
        while (w0) { int b = __ffs(w0) - 1; w0 &= w0 - 1; acc0 += Y[(size_t)(cb +      b) * HID + d]; }
        while (w1) { int b = __ffs(w1) - 1; w1 &= w1 - 1; acc1 += Y[(size_t)(cb + 32 + b) * HID + d]; }
        while (w2) { int b = __ffs(w2) - 1; w2 &= w2 - 1; acc0 += Y[(size_t)(cb + 64 + b) * HID + d]; }
        while (w3) { int b = __ffs(w3) - 1; w3 &= w3 - 1; acc1 += Y[(size_t)(cb + 96 + b) * HID + d]; }
    }
    float hv = drow[r] * (acc0 + acc1);
    // project: z = hv @ W2 (reduce over d across the wave)
    float z0 = hv * W2[d * 2 + 0];
    float z1 = hv * W2[d * 2 + 1];
    for (int off = 32; off >= 1; off >>= 1) {
        z0 += __shfl_xor(z0, off, 64);
        z1 += __shfl_xor(z1, off, 64);
    }
    if (d == 0) {
        float dc = 1.0f / sqrtf((float)(col_cnt[r] + 1));
        Zc[r * 2 + 0] = dc * z0;
        Zc[r * 2 + 1] = dc * z1;
    }
}

// ---------------- kernel 5: SpMM layer 2 off the bitmask ----------------
__global__ __launch_bounds__(256) void spmm2_kernel(const float* __restrict__ Zc,
                                                    const uint* __restrict__ bitmask,
                                                    const float* __restrict__ drow,
                                                    float* __restrict__ out)
{
    int r = blockIdx.x * 4 + (threadIdx.x >> 6);
    r = __builtin_amdgcn_readfirstlane(r);
    int lane = threadIdx.x & 63;
    float a0 = 0.0f, a1 = 0.0f;
#pragma unroll
    for (int i = 0; i < 4; i++) {
        int wi = lane + i * 64;
        uint w = bitmask[(size_t)r * 256 + wi];
        int cb = wi * 32;
        while (w) {
            int b = __ffs(w) - 1;
            w &= w - 1;
            a0 += Zc[(cb + b) * 2 + 0];
            a1 += Zc[(cb + b) * 2 + 1];
        }
    }
    for (int off = 32; off >= 1; off >>= 1) {
        a0 += __shfl_xor(a0, off, 64);
        a1 += __shfl_xor(a1, off, 64);
    }
    if (lane == 0) {
        a0 += Zc[r * 2 + 0];                     // identity (+I) term
        a1 += Zc[r * 2 + 1];
        out[r * 2 + 0] = drow[r] * a0;
        out[r * 2 + 1] = drow[r] * a1;
    }
}

extern "C" void kernel_launch(void* const* d_in, const int* in_sizes, int n_in,
                              void* d_out, int out_size, void* d_ws, size_t ws_size,
                              hipStream_t stream)
{
    const float* x    = (const float*)d_in[0];
    // d_in[1] (adj) unused: adj.flat[idx] == 1.0 by construction
    const float* xdeg = (const float*)d_in[2];
    const float* ydeg = (const float*)d_in[3];
    const float* Wm1  = (const float*)d_in[4];
    const float* bm1  = (const float*)d_in[5];
    const float* Wm2  = (const float*)d_in[6];
    const float* bm2  = (const float*)d_in[7];
    const float* W1   = (const float*)d_in[8];
    const float* W2   = (const float*)d_in[9];
    const int*   idx  = (const int*)d_in[10];
    const int E = in_sizes[10];

    float* out = (float*)d_out;                       // [N*NC]
    float* adj_mask = out + (size_t)N * NC;           // [N*N]

    // ---- workspace carve ----
    char* ws = (char*)d_ws;
    size_t off = 0;
    auto carve = [&](size_t bytes) -> void* {
        void* p = ws + off;
        off += (bytes + 255) & ~(size_t)255;
        return p;
    };
    uint* bitmask = (uint*)carve(NWORDS * sizeof(uint));
    int* col_cnt  = (int*)carve((size_t)N * sizeof(int));
    float* drow   = (float*)carve((size_t)N * sizeof(float));
    float* Y      = (float*)carve((size_t)N * HID * sizeof(float));
    float* Zc     = (float*)carve((size_t)N * NC * sizeof(float));

    hipMemsetAsync(bitmask, 0, NWORDS * sizeof(uint), stream);
    hipMemsetAsync(col_cnt, 0, (size_t)N * sizeof(int), stream);

    dedup_or_kernel<<<(E + 255) / 256, 256, 0, stream>>>(idx, E, bitmask);
    mask_kernel<<<N, 256, 0, stream>>>(bitmask, xdeg, ydeg, Wm1, bm1, Wm2, bm2,
                                       adj_mask, drow, col_cnt);
    xw1_kernel<<<N / 4, 256, 0, stream>>>(x, W1, col_cnt, Y);
    spmm1_kernel<<<N / 4, 256, 0, stream>>>(Y, bitmask, drow, col_cnt, W2, Zc);
    spmm2_kernel<<<N / 4, 256, 0, stream>>>(Zc, bitmask, drow, out);
}